// Round 2
// baseline (342.556 us; speedup 1.0000x reference)
//
#include <hip/hip_runtime.h>

// BasicBlock: y = relu(bn2(conv2(relu(bn1(conv1(x, we1))), we2)) + x)
// we{1,2} = sum_e alpha[e]*w{1,2}[e] (conv linear in weights).
//
// bf16 implicit-GEMM conv, mfma_f32_16x16x32_bf16.
//   prep:   fold experts -> w_eff bf16 [kpos][o][i], fold BN -> inv/bias
//   pass 0: conv1+bn1+relu: x (NCHW f32) -> y1 (NHWC bf16)
//   pass 1: conv2+bn2+res+relu: y1 -> out (NCHW f32)
// Block = 16x16 px tile x 64 oc, 512 threads (8 waves), K=576 from ONE
// LDS tile (18x18 px x 64ch, 144B pixel stride vs bank conflicts).
// Staging uses explicit 6-7 deep load batches for HBM latency hiding
// (round 1 was latency-bound at 1.5 TB/s with ~1 load in flight).

typedef __bf16 bf16x8 __attribute__((ext_vector_type(8)));
typedef float f32x4 __attribute__((ext_vector_type(4)));
typedef unsigned short u16;
typedef u16 u16x8 __attribute__((ext_vector_type(8)));

#define NH 112
#define NW 112
#define PIXSTRIDE 144  // bytes per pixel block in LDS (128B data + 16B pad)

__device__ __forceinline__ u16 f2b(float f) {
  unsigned u = __builtin_bit_cast(unsigned, f);
  u += 0x7FFFu + ((u >> 16) & 1u);
  return (u16)(u >> 16);
}

// ---------------------------------------------------------------------------
__global__ void prep_kernel(
    const float* __restrict__ w1, const float* __restrict__ w2,
    const float* __restrict__ alpha,
    const float* __restrict__ g1, const float* __restrict__ b1,
    const float* __restrict__ m1, const float* __restrict__ v1,
    const float* __restrict__ g2, const float* __restrict__ b2,
    const float* __restrict__ m2, const float* __restrict__ v2,
    u16* __restrict__ weff1, u16* __restrict__ weff2, float* __restrict__ bnc) {
  int idx = blockIdx.x * 256 + threadIdx.x;  // 9*64*64 = 36864
  if (idx < 36864) {
    int i = idx & 63;
    int o = (idx >> 6) & 63;
    int kpos = idx >> 12;
    int base = (o * 64 + i) * 9 + kpos;  // src [E][O][I][3][3]
    float a1 = 0.f, a2 = 0.f;
#pragma unroll
    for (int e = 0; e < 10; ++e) {
      float al = alpha[e];
      a1 += al * w1[e * 36864 + base];
      a2 += al * w2[e * 36864 + base];
    }
    weff1[idx] = f2b(a1);
    weff2[idx] = f2b(a2);
  }
  if (blockIdx.x == 0 && threadIdx.x < 64) {
    int c = threadIdx.x;
    float i1 = g1[c] * rsqrtf(v1[c] + 1e-5f);
    float i2 = g2[c] * rsqrtf(v2[c] + 1e-5f);
    bnc[c] = i1;
    bnc[64 + c] = b1[c] - m1[c] * i1;
    bnc[128 + c] = i2;
    bnc[192 + c] = b2[c] - m2[c] * i2;
  }
}

// ---------------------------------------------------------------------------
// grid = 32 b * 49 tiles = 1568 blocks, 512 threads.
// ---------------------------------------------------------------------------
template <int PASS>
__global__ __launch_bounds__(512) void conv_bn_kernel(
    const float* __restrict__ x, const u16* __restrict__ yin,
    const u16* __restrict__ weff, const float* __restrict__ bnc,
    u16* __restrict__ yout, float* __restrict__ out) {
  __shared__ alignas(16) char smem[46656];  // 18*18*144

  int tid = threadIdx.x;
  int lane = tid & 63;
  int wv = tid >> 6;
  int bid = blockIdx.x;
  int b = bid / 49;
  int r = bid % 49;
  int h0 = (r / 7) * 16;
  int w0 = (r % 7) * 16;

  // ---- stage input tile: rows h0-1..h0+16, cols w0-1..w0+16, 64 ch ----
  if constexpr (PASS == 0) {
    // NCHW fp32 -> bf16 scatter. 6912 f32x4 slots, 2 batches x 7/thread.
#pragma unroll
    for (int bat = 0; bat < 2; ++bat) {
      f32x4 v[7];
#pragma unroll
      for (int it = 0; it < 7; ++it) {
        int fid = bat * 3584 + it * 512 + tid;
        int q = fid % 6;
        int rc = fid / 6;
        int ch = rc & 63;
        int row = rc >> 6;
        int h = h0 - 1 + row;
        int wb = w0 - 4 + q * 4;
        v[it] = f32x4{0.f, 0.f, 0.f, 0.f};
        if (fid < 6912 && (unsigned)h < (unsigned)NH && (unsigned)wb <= 108u)
          v[it] = *reinterpret_cast<const f32x4*>(x + (((b * 64 + ch) * NH + h) * NW + wb));
      }
#pragma unroll
      for (int it = 0; it < 7; ++it) {
        int fid = bat * 3584 + it * 512 + tid;
        if (fid < 6912) {
          int q = fid % 6;
          int rc = fid / 6;
          int ch = rc & 63;
          int row = rc >> 6;
          int wb = w0 - 4 + q * 4;
#pragma unroll
          for (int j = 0; j < 4; ++j) {
            int col = wb + j - (w0 - 1);
            if ((unsigned)col < 18u)
              *reinterpret_cast<u16*>(smem + (row * 18 + col) * PIXSTRIDE + ch * 2) =
                  f2b(v[it][j]);
          }
        }
      }
    }
  } else {
    // NHWC bf16: 2592 16B chunks, 6 loads in flight per thread.
    u16x8 v[6];
#pragma unroll
    for (int it = 0; it < 6; ++it) {
      int cidx = it * 512 + tid;
      int c8 = cidx & 7;
      int pc = cidx >> 3;
      int col = pc % 18;
      int row = pc / 18;
      int h = h0 - 1 + row, w = w0 - 1 + col;
      v[it] = u16x8{0, 0, 0, 0, 0, 0, 0, 0};
      if (cidx < 2592 && (unsigned)h < (unsigned)NH && (unsigned)w < (unsigned)NW)
        v[it] = *reinterpret_cast<const u16x8*>(yin + (((b * NH + h) * NW + w) << 6) + c8 * 8);
    }
#pragma unroll
    for (int it = 0; it < 6; ++it) {
      int cidx = it * 512 + tid;
      if (cidx < 2592) {
        int c8 = cidx & 7;
        int pc = cidx >> 3;
        int col = pc % 18;
        int row = pc / 18;
        *reinterpret_cast<u16x8*>(smem + (row * 18 + col) * PIXSTRIDE + c8 * 16) = v[it];
      }
    }
  }
  __syncthreads();

  // ---- MFMA: 9 kpos x 2 ksteps; wave owns Mfrags (2wv, 2wv+1) x 4 Nfrags ----
  f32x4 acc[2][4];
#pragma unroll
  for (int mf = 0; mf < 2; ++mf)
#pragma unroll
    for (int nf = 0; nf < 4; ++nf) acc[mf][nf] = f32x4{0.f, 0.f, 0.f, 0.f};

  int ol = lane & 15;
  int kg = lane >> 4;
  int f0 = wv * 2;

#pragma unroll
  for (int kh = 0; kh < 3; ++kh)
#pragma unroll
    for (int kw = 0; kw < 3; ++kw) {
      int kpos = kh * 3 + kw;
      bf16x8 bf[2][4];
#pragma unroll
      for (int ks = 0; ks < 2; ++ks)
#pragma unroll
        for (int nf = 0; nf < 4; ++nf) {
          const u16* p = weff + ((kpos * 64 + nf * 16 + ol) * 64 + ks * 32 + kg * 8);
          bf[ks][nf] = __builtin_bit_cast(bf16x8, *reinterpret_cast<const u16x8*>(p));
        }
#pragma unroll
      for (int ks = 0; ks < 2; ++ks)
#pragma unroll
        for (int mf = 0; mf < 2; ++mf) {
          int off = ((f0 + mf + kh) * 18 + ol + kw) * PIXSTRIDE + ks * 64 + kg * 16;
          bf16x8 af = *reinterpret_cast<const bf16x8*>(smem + off);
#pragma unroll
          for (int nf = 0; nf < 4; ++nf)
            acc[mf][nf] =
                __builtin_amdgcn_mfma_f32_16x16x32_bf16(af, bf[ks][nf], acc[mf][nf], 0, 0, 0);
        }
    }

  // ---- epilogue ----
  float inv[4], bias[4];
#pragma unroll
  for (int nf = 0; nf < 4; ++nf) {
    int o = nf * 16 + ol;
    inv[nf] = bnc[PASS * 128 + o];
    bias[nf] = bnc[PASS * 128 + 64 + o];
  }
  __syncthreads();  // stage tile reads done; reuse smem

  if constexpr (PASS == 0) {
    u16* ys = reinterpret_cast<u16*>(smem);  // [256 px][72]  (pad vs banks)
#pragma unroll
    for (int mf = 0; mf < 2; ++mf)
#pragma unroll
      for (int nf = 0; nf < 4; ++nf) {
        int o = nf * 16 + ol;
#pragma unroll
        for (int rg = 0; rg < 4; ++rg) {
          int p = (f0 + mf) * 16 + kg * 4 + rg;
          ys[p * 72 + o] = f2b(fmaxf(acc[mf][nf][rg] * inv[nf] + bias[nf], 0.f));
        }
      }
    __syncthreads();
#pragma unroll
    for (int it = 0; it < 4; ++it) {
      int cidx = it * 512 + tid;  // 2048 chunks
      int c8 = cidx & 7, p = cidx >> 3;
      int h = h0 + (p >> 4), w = w0 + (p & 15);
      *reinterpret_cast<u16x8*>(yout + (((b * NH + h) * NW + w) << 6) + c8 * 8) =
          *reinterpret_cast<const u16x8*>(ys + p * 72 + c8 * 8);
    }
  } else {
    float* tb = reinterpret_cast<float*>(smem);  // [64 oc][132 f32], 128 px half
#pragma unroll
    for (int half = 0; half < 2; ++half) {
      if ((wv >> 2) == half) {
#pragma unroll
        for (int mf = 0; mf < 2; ++mf)
#pragma unroll
          for (int nf = 0; nf < 4; ++nf) {
            int o = nf * 16 + ol;
            int lp = (f0 + mf) * 16 + kg * 4 - half * 128;
            f32x4 t;
#pragma unroll
            for (int rg = 0; rg < 4; ++rg) t[rg] = acc[mf][nf][rg] * inv[nf] + bias[nf];
            *reinterpret_cast<f32x4*>(tb + o * 132 + lp) = t;
          }
      }
      __syncthreads();
#pragma unroll
      for (int it = 0; it < 4; ++it) {
        int cidx = it * 512 + tid;  // 2048 f32x4 per half
        int g = cidx & 31, o = cidx >> 5;
        int p = half * 128 + g * 4;
        int h = h0 + (p >> 4), w = w0 + (p & 15);
        int gi = ((b * 64 + o) * NH + h) * NW + w;
        f32x4 vv = *reinterpret_cast<const f32x4*>(tb + o * 132 + g * 4);
        f32x4 xr = *reinterpret_cast<const f32x4*>(x + gi);
#pragma unroll
        for (int rg = 0; rg < 4; ++rg) vv[rg] = fmaxf(vv[rg] + xr[rg], 0.f);
        *reinterpret_cast<f32x4*>(out + gi) = vv;
      }
      __syncthreads();
    }
  }
}

// ---------------------------------------------------------------------------
extern "C" void kernel_launch(void* const* d_in, const int* in_sizes, int n_in,
                              void* d_out, int out_size, void* d_ws, size_t ws_size,
                              hipStream_t stream) {
  const float* x = (const float*)d_in[0];
  const float* w1 = (const float*)d_in[1];
  const float* w2 = (const float*)d_in[2];
  const float* alpha = (const float*)d_in[3];
  const float* g1 = (const float*)d_in[4];
  const float* b1 = (const float*)d_in[5];
  const float* m1 = (const float*)d_in[6];
  const float* v1 = (const float*)d_in[7];
  const float* g2 = (const float*)d_in[8];
  const float* b2 = (const float*)d_in[9];
  const float* m2 = (const float*)d_in[10];
  const float* v2 = (const float*)d_in[11];
  float* out = (float*)d_out;

  char* ws = (char*)d_ws;
  u16* weff1 = (u16*)ws;
  u16* weff2 = (u16*)(ws + 73728);
  float* bnc = (float*)(ws + 147456);
  u16* y1 = (u16*)(ws + 148480);  // 51380224 B, NHWC bf16

  prep_kernel<<<144, 256, 0, stream>>>(w1, w2, alpha, g1, b1, m1, v1,
                                       g2, b2, m2, v2, weff1, weff2, bnc);
  conv_bn_kernel<0><<<1568, 512, 0, stream>>>(x, nullptr, weff1, bnc, y1, nullptr);
  conv_bn_kernel<1><<<1568, 512, 0, stream>>>(x, y1, weff2, bnc, nullptr, out);
}

// Round 3
// 311.826 us; speedup vs baseline: 1.0985x; 1.0985x over previous
//
#include <hip/hip_runtime.h>

// BasicBlock: y = relu(bn2(conv2(relu(bn1(conv1(x, we1))), we2)) + x)
// we{1,2} = sum_e alpha[e]*w{1,2}[e].
//
// All conv staging is linear global_load_lds (width 16) from a padded,
// chunk-swizzled NHWC bf16 image:
//   x_pad[b][114][114][64]  (in d_out; borders zeroed)
//   y1_pad[b][114][114][64] (in ws;    borders zeroed)
// Within each 128B pixel, the eight 16B channel-chunks are stored permuted:
// slot = c8 ^ ((2*h_pad + w_pad) & 7). Tile origins are multiples of 16, so
// readers recover the key from tile-local coords; the swizzle kills the
// 16-way bank conflict of stride-128 ds_read_b128 A-fragment reads.
//
// passes: border_zero -> transform(x->x_pad) -> prep(weights/bn) ->
//         conv<0>(x_pad -> y1_pad) -> conv<1>(y1_pad + x -> out)

typedef __bf16 bf16x8 __attribute__((ext_vector_type(8)));
typedef float f32x4 __attribute__((ext_vector_type(4)));
typedef unsigned short u16;
typedef u16 u16x8 __attribute__((ext_vector_type(8)));

#define NH 112
#define NW 112
#define PH 114
#define PW 114
#define PROWB (PW * 128)  // 14592 bytes per padded NHWC row

__device__ __forceinline__ u16 f2b(float f) {
  unsigned u = __builtin_bit_cast(unsigned, f);
  u += 0x7FFFu + ((u >> 16) & 1u);
  return (u16)(u >> 16);
}

__device__ __forceinline__ void gl_lds16(const void* g, void* l) {
  __builtin_amdgcn_global_load_lds(
      (const __attribute__((address_space(1))) unsigned int*)g,
      (__attribute__((address_space(3))) unsigned int*)l, 16, 0, 0);
}

// ---------------------------------------------------------------------------
// zero the 1-px borders of both padded buffers (452 px/image each)
__global__ void border_zero(u16* __restrict__ a, u16* __restrict__ bbuf) {
  int idx = blockIdx.x * 256 + threadIdx.x;  // 2*32*452*8 = 231424 chunks
  if (idx >= 231424) return;
  int c8 = idx & 7;
  int t = idx >> 3;
  int buf = t >= 14464;
  t -= buf * 14464;
  int img = t / 452, e = t % 452;
  int h, w;
  if (e < 114) { h = 0; w = e; }
  else if (e < 228) { h = 113; w = e - 114; }
  else if (e < 340) { h = e - 227; w = 0; }
  else { h = e - 339; w = 113; }
  u16* base = buf ? bbuf : a;
  u16x8 z = {0, 0, 0, 0, 0, 0, 0, 0};
  *reinterpret_cast<u16x8*>(base + (((long)img * PH + h) * PW + w) * 64 + c8 * 8) = z;
}

// ---------------------------------------------------------------------------
// x NCHW fp32 -> x_pad NHWC bf16 (padded + chunk-swizzled). block = (b,h).
__global__ __launch_bounds__(256) void transform_kernel(const float* __restrict__ x,
                                                        u16* __restrict__ xpad) {
  __shared__ alignas(16) u16 t[7168];  // [112 px][64 ch], xor-swizzled bytes
  int tid = threadIdx.x, bid = blockIdx.x;
  int b = bid / NH, h = bid % NH;
  const float* src = x + (long)b * 64 * 12544 + h * NW;
  f32x4 v[7];
#pragma unroll
  for (int it = 0; it < 7; ++it) {
    int fid = it * 256 + tid;  // 1792 = 64 ch * 28 quads
    int c = fid / 28, wq = fid % 28;
    v[it] = *reinterpret_cast<const f32x4*>(src + c * 12544 + wq * 4);
  }
#pragma unroll
  for (int it = 0; it < 7; ++it) {
    int fid = it * 256 + tid;
    int c = fid / 28, wq = fid % 28;
    int key = (wq & 7) << 4;
#pragma unroll
    for (int j = 0; j < 4; ++j) {
      int px = wq * 4 + j;
      *reinterpret_cast<u16*>((char*)t + px * 128 + ((c * 2) ^ key)) = f2b(v[it][j]);
    }
  }
  __syncthreads();
  int hp = h + 1;
  u16* rowb = xpad + (((long)b * PH + hp) * PW) * 64;
#pragma unroll
  for (int it = 0; it < 4; ++it) {
    int cidx = it * 256 + tid;
    if (cidx < 896) {  // 112 px * 8 chunks
      int c8 = cidx & 7, px = cidx >> 3;
      int lchunk = c8 ^ ((px >> 2) & 7);
      u16x8 vv = *reinterpret_cast<const u16x8*>((const char*)t + px * 128 + lchunk * 16);
      int wp = px + 1;
      int gkey = (2 * hp + wp) & 7;
      *reinterpret_cast<u16x8*>(rowb + (long)wp * 64 + ((c8 ^ gkey) * 8)) = vv;
    }
  }
}

// ---------------------------------------------------------------------------
// fold experts -> w_eff bf16 [kpos][o][i] + folded BN constants
__global__ void prep_kernel(
    const float* __restrict__ w1, const float* __restrict__ w2,
    const float* __restrict__ alpha,
    const float* __restrict__ g1, const float* __restrict__ b1,
    const float* __restrict__ m1, const float* __restrict__ v1,
    const float* __restrict__ g2, const float* __restrict__ b2,
    const float* __restrict__ m2, const float* __restrict__ v2,
    u16* __restrict__ weff1, u16* __restrict__ weff2, float* __restrict__ bnc) {
  int idx = blockIdx.x * 256 + threadIdx.x;  // 36864
  if (idx < 36864) {
    int i = idx & 63;
    int o = (idx >> 6) & 63;
    int kpos = idx >> 12;
    int base = (o * 64 + i) * 9 + kpos;  // src [E][O][I][3][3]
    float a1 = 0.f, a2 = 0.f;
#pragma unroll
    for (int e = 0; e < 10; ++e) {
      float al = alpha[e];
      a1 += al * w1[e * 36864 + base];
      a2 += al * w2[e * 36864 + base];
    }
    weff1[idx] = f2b(a1);
    weff2[idx] = f2b(a2);
  }
  if (blockIdx.x == 0 && threadIdx.x < 64) {
    int c = threadIdx.x;
    float i1 = g1[c] * rsqrtf(v1[c] + 1e-5f);
    float i2 = g2[c] * rsqrtf(v2[c] + 1e-5f);
    bnc[c] = i1;
    bnc[64 + c] = b1[c] - m1[c] * i1;
    bnc[128 + c] = i2;
    bnc[192 + c] = b2[c] - m2[c] * i2;
  }
}

// ---------------------------------------------------------------------------
// conv pass. 16x16 px x 64 oc per block, 512 threads, grid 32*49.
// PASS 0: xin=x_pad -> bn1+relu -> y1_pad (swizzled NHWC bf16)
// PASS 1: xin=y1_pad -> bn2 + residual(x) + relu -> out (NCHW f32)
// ---------------------------------------------------------------------------
template <int PASS>
__global__ __launch_bounds__(512) void conv_bn_kernel(
    const u16* __restrict__ xin, const float* __restrict__ x,
    const u16* __restrict__ weff, const float* __restrict__ bnc,
    u16* __restrict__ ypad, float* __restrict__ out) {
  __shared__ alignas(1024) char smem[41984];  // 18*18*128 + tail slack

  int tid = threadIdx.x;
  int lane = tid & 63;
  int wv = tid >> 6;
  int bid = blockIdx.x;
  int b = bid / 49;
  int r = bid % 49;
  int h0 = (r / 7) * 16;  // padded-coord tile origin (== unpadded h0)
  int w0 = (r % 7) * 16;

  // ---- stage 18x18 px window: pure linear global_load_lds ----
  const char* srcb = (const char*)(xin + (((long)b * PH + h0) * PW + w0) * 64);
  for (int c = wv; c < 41; c += 8) {
    int byte = c * 1024 + lane * 16;
    int row = byte / 2304;  // 18 px * 128 B per tile row
    int rem = byte - row * 2304;
    if (c < 40 || lane < 32)
      gl_lds16(srcb + (long)row * PROWB + rem, smem + c * 1024);
  }
  __syncthreads();

  // ---- MFMA: 9 kpos x 2 ksteps; wave owns Mfrags (2wv,2wv+1) x 4 Nfrags ----
  f32x4 acc[2][4];
#pragma unroll
  for (int mf = 0; mf < 2; ++mf)
#pragma unroll
    for (int nf = 0; nf < 4; ++nf) acc[mf][nf] = f32x4{0.f, 0.f, 0.f, 0.f};

  int ol = lane & 15;
  int kg = lane >> 4;
  int f0 = wv * 2;

#pragma unroll
  for (int kh = 0; kh < 3; ++kh)
#pragma unroll
    for (int kw = 0; kw < 3; ++kw) {
      int kpos = kh * 3 + kw;
      bf16x8 bf[2][4];
#pragma unroll
      for (int ks = 0; ks < 2; ++ks)
#pragma unroll
        for (int nf = 0; nf < 4; ++nf) {
          const u16* p = weff + ((kpos * 64 + nf * 16 + ol) * 64 + ks * 32 + kg * 8);
          bf[ks][nf] = __builtin_bit_cast(bf16x8, *reinterpret_cast<const u16x8*>(p));
        }
#pragma unroll
      for (int ks = 0; ks < 2; ++ks)
#pragma unroll
        for (int mf = 0; mf < 2; ++mf) {
          int rr = f0 + mf + kh;
          int col = ol + kw;
          int slot = ((ks << 2) | kg) ^ ((2 * rr + col) & 7);
          bf16x8 af =
              *reinterpret_cast<const bf16x8*>(smem + (rr * 18 + col) * 128 + slot * 16);
#pragma unroll
          for (int nf = 0; nf < 4; ++nf)
            acc[mf][nf] =
                __builtin_amdgcn_mfma_f32_16x16x32_bf16(af, bf[ks][nf], acc[mf][nf], 0, 0, 0);
        }
    }

  // ---- epilogue ----
  float inv[4], bias[4];
#pragma unroll
  for (int nf = 0; nf < 4; ++nf) {
    int o = nf * 16 + ol;
    inv[nf] = bnc[PASS * 128 + o];
    bias[nf] = bnc[PASS * 128 + 64 + o];
  }
  __syncthreads();  // done with A tile; reuse smem

  if constexpr (PASS == 0) {
    u16* ys = reinterpret_cast<u16*>(smem);  // [256 px][72]
#pragma unroll
    for (int mf = 0; mf < 2; ++mf)
#pragma unroll
      for (int nf = 0; nf < 4; ++nf) {
        int o = nf * 16 + ol;
#pragma unroll
        for (int rg = 0; rg < 4; ++rg) {
          int p = (f0 + mf) * 16 + kg * 4 + rg;
          ys[p * 72 + o] = f2b(fmaxf(acc[mf][nf][rg] * inv[nf] + bias[nf], 0.f));
        }
      }
    __syncthreads();
#pragma unroll
    for (int it = 0; it < 4; ++it) {
      int cidx = it * 512 + tid;  // 2048 chunks
      int c8 = cidx & 7, p = cidx >> 3;
      int hp = h0 + (p >> 4) + 1, wp = w0 + (p & 15) + 1;
      int gkey = (2 * hp + wp) & 7;
      *reinterpret_cast<u16x8*>(ypad + (((long)b * PH + hp) * PW + wp) * 64 +
                                ((c8 ^ gkey) * 8)) =
          *reinterpret_cast<const u16x8*>(ys + p * 72 + c8 * 8);
    }
  } else {
    float* tb = reinterpret_cast<float*>(smem);  // [64 oc][132 f32] per half
#pragma unroll
    for (int half = 0; half < 2; ++half) {
      if ((wv >> 2) == half) {
#pragma unroll
        for (int mf = 0; mf < 2; ++mf)
#pragma unroll
          for (int nf = 0; nf < 4; ++nf) {
            int o = nf * 16 + ol;
            int lp = (f0 + mf) * 16 + kg * 4 - half * 128;
            f32x4 t;
#pragma unroll
            for (int rg = 0; rg < 4; ++rg) t[rg] = acc[mf][nf][rg] * inv[nf] + bias[nf];
            *reinterpret_cast<f32x4*>(tb + o * 132 + lp) = t;
          }
      }
      __syncthreads();
#pragma unroll
      for (int it = 0; it < 4; ++it) {
        int cidx = it * 512 + tid;  // 2048 f32x4 per half
        int g = cidx & 31, o = cidx >> 5;
        int p = half * 128 + g * 4;
        int h = h0 + (p >> 4), w = w0 + (p & 15);
        int gi = ((b * 64 + o) * NH + h) * NW + w;
        f32x4 vv = *reinterpret_cast<const f32x4*>(tb + o * 132 + g * 4);
        f32x4 xr = *reinterpret_cast<const f32x4*>(x + gi);
#pragma unroll
        for (int rg = 0; rg < 4; ++rg) vv[rg] = fmaxf(vv[rg] + xr[rg], 0.f);
        *reinterpret_cast<f32x4*>(out + gi) = vv;
      }
      __syncthreads();
    }
  }
}

// ---------------------------------------------------------------------------
extern "C" void kernel_launch(void* const* d_in, const int* in_sizes, int n_in,
                              void* d_out, int out_size, void* d_ws, size_t ws_size,
                              hipStream_t stream) {
  const float* x = (const float*)d_in[0];
  const float* w1 = (const float*)d_in[1];
  const float* w2 = (const float*)d_in[2];
  const float* alpha = (const float*)d_in[3];
  const float* g1 = (const float*)d_in[4];
  const float* b1 = (const float*)d_in[5];
  const float* m1 = (const float*)d_in[6];
  const float* v1 = (const float*)d_in[7];
  const float* g2 = (const float*)d_in[8];
  const float* b2 = (const float*)d_in[9];
  const float* m2 = (const float*)d_in[10];
  const float* v2 = (const float*)d_in[11];
  float* out = (float*)d_out;

  char* ws = (char*)d_ws;
  u16* weff1 = (u16*)ws;                 // 73728 B
  u16* weff2 = (u16*)(ws + 73728);       // 73728 B
  float* bnc = (float*)(ws + 147456);    // 1024 B
  u16* y1pad = (u16*)(ws + 148480);      // 32*114*114*64*2 = 53231616 B (+slack)
  u16* xpad = (u16*)d_out;               // 53231616 B <= 102760448 B; dead by pass 1

  border_zero<<<904, 256, 0, stream>>>(xpad, y1pad);
  transform_kernel<<<32 * NH, 256, 0, stream>>>(x, xpad);
  prep_kernel<<<144, 256, 0, stream>>>(w1, w2, alpha, g1, b1, m1, v1,
                                       g2, b2, m2, v2, weff1, weff2, bnc);
  conv_bn_kernel<0><<<1568, 512, 0, stream>>>(xpad, x, weff1, bnc, y1pad, nullptr);
  conv_bn_kernel<1><<<1568, 512, 0, stream>>>(y1pad, x, weff2, bnc, nullptr, out);
}